// Round 1
// baseline (20676.962 us; speedup 1.0000x reference)
//
#include <hip/hip_runtime.h>
#include <hip/hip_bf16.h>
#include <math.h>

// Problem constants
#define VV   32000
#define DD   300
#define HU   300
#define NC   3
#define BB   128
#define TT   512
#define N4H  1200
#define CHUNK 64
#define NCHUNK (TT / CHUNK)

// Recurrent kernel partition
#define GC   15   // col groups (units)
#define GR   16   // row groups
#define RPW  8    // rows per WG (BB/GR)
#define UPW  20   // units per WG (HU/GC)
#define KCH  12   // k-chunks (threads 0..239 active in GEMM)
#define KLEN 25   // k per chunk (KCH*KLEN = 300)

// Workspace layout (floats): [zx][h_buf][c_state][flags(int)]
static constexpr size_t ZX_F   = (size_t)BB * CHUNK * N4H;  // 9,830,400
static constexpr size_t HBUF_F = 2 * (size_t)BB * HU;       // 76,800
static constexpr size_t CST_F  = (size_t)BB * HU;           // 38,400
static constexpr size_t FLAG_I = (size_t)GR * TT;           // 8,192 ints

typedef __attribute__((ext_vector_type(8))) short bf16x8;
typedef __attribute__((ext_vector_type(4))) float f32x4;

__device__ __forceinline__ short f2bf(float f) {
    unsigned u = __float_as_uint(f);
    u += 0x7fff + ((u >> 16) & 1);   // round-to-nearest-even
    return (short)(u >> 16);
}
__device__ __forceinline__ float sigm(float x) { return 1.f / (1.f + __expf(-x)); }
__device__ __forceinline__ float tanh_(float x) { return 1.f - 2.f / (__expf(2.f * x) + 1.f); }

// ---------------------------------------------------------------------------
// init: zero h_buf, c_state, flags, out[0]  (ws is poisoned 0xAA every launch)
// ---------------------------------------------------------------------------
__global__ void init_kernel(float* __restrict__ hbuf, int* __restrict__ flags,
                            float* __restrict__ out) {
    size_t i = (size_t)blockIdx.x * 256 + threadIdx.x;
    if (i < HBUF_F + CST_F) hbuf[i] = 0.f;       // h_buf + c_state contiguous
    if (i < FLAG_I) flags[i] = 0;
    if (i == 0) out[0] = 0.f;
}

// ---------------------------------------------------------------------------
// Phase 1: zx[b][tc][n] = emb[ids[b][t0+tc]] @ W_lstm[0:300] + b_lstm   (bf16 MFMA)
// WG tile: M=256 rows, N=80 cols, K=320 (300 zero-padded). 4 waves, wave = 64x80.
// grid = (8192/256, 1200/80) = (32, 15)
// ---------------------------------------------------------------------------
__global__ __launch_bounds__(256) void zx_gemm(
    const float* __restrict__ emb, const int* __restrict__ ids,
    const float* __restrict__ Wl, const float* __restrict__ bl,
    float* __restrict__ zx, int t0)
{
    __shared__ short A_l[256 * 40];   // [row][k] pad 32->40 shorts
    __shared__ short B_l[80 * 40];    // [col][k] (transposed)
    __shared__ int   ids_l[256];

    const int tid = threadIdx.x;
    const int m0  = blockIdx.x * 256;
    const int n0  = blockIdx.y * 80;
    const int wv  = tid >> 6, ln = tid & 63;

    {   // per-row embedding id
        int m = m0 + tid;
        int b = m >> 6, tc = m & (CHUNK - 1);
        ids_l[tid] = ids[b * TT + t0 + tc];
    }

    f32x4 acc[4][5];
    for (int i = 0; i < 4; ++i)
        for (int j = 0; j < 5; ++j)
            acc[i][j] = (f32x4){0.f, 0.f, 0.f, 0.f};

    for (int k0 = 0; k0 < 320; k0 += 32) {
        __syncthreads();
        // stage A: 256 rows x 32 k, one row per thread (float4 x8, guard k<300)
        {
            const float* src = emb + (size_t)ids_l[tid] * DD;
            #pragma unroll
            for (int q = 0; q < 8; ++q) {
                int kg = k0 + q * 4;
                float4 v;
                if (kg < DD) v = *(const float4*)(src + kg);
                else         v = make_float4(0.f, 0.f, 0.f, 0.f);
                short4 s; s.x = f2bf(v.x); s.y = f2bf(v.y); s.z = f2bf(v.z); s.w = f2bf(v.w);
                *(short4*)&A_l[tid * 40 + q * 4] = s;
            }
        }
        // stage B (transposed): 80 cols x 32 k. thread: kk=tid>>3, 10 cols each
        {
            int kk = tid >> 3;
            int c0 = (tid & 7) * 10;
            int kg = k0 + kk;
            #pragma unroll
            for (int c = 0; c < 10; ++c) {
                float v = (kg < DD) ? Wl[(size_t)kg * N4H + n0 + c0 + c] : 0.f;
                B_l[(c0 + c) * 40 + kk] = f2bf(v);
            }
        }
        __syncthreads();
        // fragments + MFMA. A[m=lane&15][k=quad*8+j], B[k=quad*8+j][n=lane&15]
        const int koff = (ln >> 4) * 8;
        bf16x8 afr[4], bfr[5];
        #pragma unroll
        for (int mt = 0; mt < 4; ++mt) {
            int row = wv * 64 + mt * 16 + (ln & 15);
            afr[mt] = *(const bf16x8*)&A_l[row * 40 + koff];
        }
        #pragma unroll
        for (int nt = 0; nt < 5; ++nt) {
            int col = nt * 16 + (ln & 15);
            bfr[nt] = *(const bf16x8*)&B_l[col * 40 + koff];
        }
        #pragma unroll
        for (int mt = 0; mt < 4; ++mt)
            #pragma unroll
            for (int nt = 0; nt < 5; ++nt)
                acc[mt][nt] = __builtin_amdgcn_mfma_f32_16x16x32_bf16(
                    afr[mt], bfr[nt], acc[mt][nt], 0, 0, 0);
    }
    // epilogue: C row=(lane>>4)*4+reg, col=lane&15; add bias
    #pragma unroll
    for (int mt = 0; mt < 4; ++mt) {
        #pragma unroll
        for (int nt = 0; nt < 5; ++nt) {
            #pragma unroll
            for (int rg = 0; rg < 4; ++rg) {
                int row = m0 + wv * 64 + mt * 16 + (ln >> 4) * 4 + rg;
                int col = n0 + nt * 16 + (ln & 15);
                zx[(size_t)row * N4H + col] = acc[mt][nt][rg] + bl[col];
            }
        }
    }
}

// ---------------------------------------------------------------------------
// Phase 2: persistent recurrent kernel. 240 WGs = 16 row-groups x 15 col-groups.
// W_h slice lives in registers (thread owns 4 cols x 25 k = 100 VGPRs).
// Per-step sync only within a row-group (15 WGs) via flags[rg][t].
// blockIdx = rg + 16*cg so a row-group shares an XCD (round-robin heuristic).
// ---------------------------------------------------------------------------
__global__ __launch_bounds__(256) void lstm_rec(
    const float* __restrict__ zx, const float* __restrict__ Wl,
    const int* __restrict__ lens, float* __restrict__ hbuf,
    float* __restrict__ cst, int* __restrict__ flags, int t0)
{
    const int tid = threadIdx.x;
    const int rg  = blockIdx.x % GR;
    const int cgi = blockIdx.x / GR;
    const int r0  = rg * RPW;
    const int u0  = cgi * UPW;

    // GEMM role: cc in 0..19 (4 cols), kc in 0..11 (25 k); tid>=240 idle in GEMM
    const int cc = tid % 20;
    const int kc = tid / 20;
    const bool gemm_act = (kc < KCH);

    // local col -> global gate col (4 consecutive cols never span a gate: 20%4==0)
    const int lc0  = cc * 4;
    const int gate = lc0 / UPW;
    const int ncol = 300 * gate + u0 + (lc0 % UPW);

    float4 w[KLEN];
    if (gemm_act) {
        #pragma unroll
        for (int j = 0; j < KLEN; ++j) {
            int kh = kc * KLEN + j;  // h index
            w[j] = *(const float4*)(Wl + (size_t)(DD + kh) * N4H + ncol);
        }
    }

    __shared__ float h_l[RPW][304];        // staged h_{t-1}, full 300 cols
    __shared__ float zp[KCH][RPW][80];     // k-chunk partial sums
    __shared__ float c_l[RPW][UPW];        // private cell state slice

    // gate role (tid < 160): u = tid%20, r = tid/20
    int g_u = tid % UPW, g_r = tid / UPW;
    int mylen = 0;
    if (tid < RPW * UPW) {
        c_l[g_r][g_u] = cst[(size_t)(r0 + g_r) * HU + u0 + g_u];
        mylen = lens[r0 + g_r];
    }
    __syncthreads();

    for (int tc = 0; tc < CHUNK; ++tc) {
        const int t = t0 + tc;
        // wait for all col-groups of this row-group to finish step t-1
        if (t > 0) {
            if (tid == 0) {
                while (__hip_atomic_load(&flags[rg * TT + (t - 1)],
                                         __ATOMIC_ACQUIRE, __HIP_MEMORY_SCOPE_AGENT) < GC) {
                    __builtin_amdgcn_s_sleep(1);
                }
            }
            __syncthreads();
            __threadfence();   // invalidate caches: h written by other CUs/XCDs
        }
        // stage h_{t-1} (parity buffer t&1)
        {
            const float* hsrc = hbuf + (size_t)(t & 1) * BB * HU;
            for (int i = tid; i < RPW * HU; i += 256) {
                int r = i / HU, k = i % HU;
                h_l[r][k] = hsrc[(size_t)(r0 + r) * HU + k];
            }
        }
        __syncthreads();
        // h @ W_h partials: per thread 8 rows x 25 k x 4 cols (w in registers)
        if (gemm_act) {
            #pragma unroll
            for (int r = 0; r < RPW; ++r) {
                float ax = 0.f, ay = 0.f, az = 0.f, aw = 0.f;
                #pragma unroll
                for (int j = 0; j < KLEN; ++j) {
                    float hv = h_l[r][kc * KLEN + j];
                    ax += hv * w[j].x; ay += hv * w[j].y;
                    az += hv * w[j].z; aw += hv * w[j].w;
                }
                float4 o; o.x = ax; o.y = ay; o.z = az; o.w = aw;
                *(float4*)&zp[kc][r][lc0] = o;
            }
        }
        __syncthreads();
        // reduce + gates + h/c update (160 threads)
        if (tid < RPW * UPW) {
            const int b = r0 + g_r;
            float z4[4];
            #pragma unroll
            for (int gg = 0; gg < 4; ++gg) {
                float s = 0.f;
                #pragma unroll
                for (int k2 = 0; k2 < KCH; ++k2) s += zp[k2][g_r][gg * UPW + g_u];
                s += zx[((size_t)b * CHUNK + tc) * N4H + 300 * gg + u0 + g_u];
                z4[gg] = s;
            }
            float ig = sigm(z4[0]);
            float jg = tanh_(z4[1]);
            float fg = sigm(z4[2] + 1.0f);   // FORGET_BIAS
            float og = sigm(z4[3]);
            float c_old = c_l[g_r][g_u];
            float c_new = c_old * fg + ig * jg;
            float h_new = tanh_(c_new) * og;
            bool upd = (t < mylen);
            float h_old = h_l[g_r][u0 + g_u];
            float ho = upd ? h_new : h_old;
            float co = upd ? c_new : c_old;
            c_l[g_r][g_u] = co;
            hbuf[(size_t)((t + 1) & 1) * BB * HU + (size_t)b * HU + u0 + g_u] = ho;
        }
        __threadfence();     // make h visible device-wide before flagging
        __syncthreads();
        if (tid == 0)
            __hip_atomic_fetch_add(&flags[rg * TT + t], 1,
                                   __ATOMIC_RELEASE, __HIP_MEMORY_SCOPE_AGENT);
    }
    __syncthreads();
    if (tid < RPW * UPW)
        cst[(size_t)(r0 + g_r) * HU + u0 + g_u] = c_l[g_r][g_u];
}

// ---------------------------------------------------------------------------
// Phase 3: logits = h_final @ W_dense + b_dense; log-softmax NLL; mean loss.
// One wave per batch row. h_final is in h_buf parity 0 (T=512 even).
// ---------------------------------------------------------------------------
__global__ __launch_bounds__(64) void cls_kernel(
    const float* __restrict__ hbuf, const float* __restrict__ Wd,
    const float* __restrict__ bd, const int* __restrict__ labels,
    float* __restrict__ out)
{
    const int b = blockIdx.x;
    const int ln = threadIdx.x;
    const float* h = hbuf + (size_t)b * HU;   // parity 0
    float p0 = 0.f, p1 = 0.f, p2 = 0.f;
    for (int k = ln; k < HU; k += 64) {
        float hv = h[k];
        p0 += hv * Wd[k * 3 + 0];
        p1 += hv * Wd[k * 3 + 1];
        p2 += hv * Wd[k * 3 + 2];
    }
    #pragma unroll
    for (int off = 32; off > 0; off >>= 1) {
        p0 += __shfl_down(p0, off);
        p1 += __shfl_down(p1, off);
        p2 += __shfl_down(p2, off);
    }
    if (ln == 0) {
        float l0 = p0 + bd[0], l1 = p1 + bd[1], l2 = p2 + bd[2];
        float m = fmaxf(l0, fmaxf(l1, l2));
        float lse = m + logf(__expf(l0 - m) + __expf(l1 - m) + __expf(l2 - m));
        int lab = labels[b];
        float sel = (lab == 0) ? l0 : ((lab == 1) ? l1 : l2);
        float nll = lse - sel;
        out[1 + b * 3 + 0] = l0;
        out[1 + b * 3 + 1] = l1;
        out[1 + b * 3 + 2] = l2;
        atomicAdd(out, nll * (1.0f / BB));
    }
}

// ---------------------------------------------------------------------------
extern "C" void kernel_launch(void* const* d_in, const int* in_sizes, int n_in,
                              void* d_out, int out_size, void* d_ws, size_t ws_size,
                              hipStream_t stream) {
    const int*   ids  = (const int*)d_in[0];
    const int*   lens = (const int*)d_in[1];
    const int*   labs = (const int*)d_in[2];
    const float* emb  = (const float*)d_in[3];
    const float* Wl   = (const float*)d_in[4];
    const float* bl   = (const float*)d_in[5];
    const float* Wd   = (const float*)d_in[6];
    const float* bd   = (const float*)d_in[7];
    float* out = (float*)d_out;

    float* zx   = (float*)d_ws;
    float* hbuf = zx + ZX_F;
    float* cst  = hbuf + HBUF_F;
    int*   flags = (int*)(cst + CST_F);

    {   // zero h/c/flags/out[0]
        int n = (int)((HBUF_F + CST_F + 255) / 256);
        init_kernel<<<n, 256, 0, stream>>>(hbuf, flags, out);
    }
    for (int c = 0; c < NCHUNK; ++c) {
        int t0 = c * CHUNK;
        zx_gemm<<<dim3(32, 15), 256, 0, stream>>>(emb, ids, Wl, bl, zx, t0);
        lstm_rec<<<GR * GC, 256, 0, stream>>>(zx, Wl, lens, hbuf, cst, flags, t0);
    }
    cls_kernel<<<BB, 64, 0, stream>>>(hbuf, Wd, bd, labs, out);
}

// Round 2
// 2953.926 us; speedup vs baseline: 6.9998x; 6.9998x over previous
//
#include <hip/hip_runtime.h>
#include <hip/hip_bf16.h>
#include <math.h>

// Problem constants
#define VV   32000
#define DD   300
#define HU   300
#define NC   3
#define BB   128
#define TT   512
#define N4H  1200
#define CHUNK 64
#define NCHUNK (TT / CHUNK)

// Recurrent kernel partition
#define GC   15   // col groups (units)
#define GR   16   // row groups
#define RPW  8    // rows per WG (BB/GR)
#define UPW  20   // units per WG (HU/GC)
#define KCH  12   // k-chunks (threads 0..239 active in GEMM)
#define KLEN 25   // k per chunk (KCH*KLEN = 300)

// Workspace layout (floats): [zx][h_buf][c_state][flags(int)]
static constexpr size_t ZX_F   = (size_t)BB * CHUNK * N4H;  // 9,830,400
static constexpr size_t HBUF_F = 2 * (size_t)BB * HU;       // 76,800
static constexpr size_t CST_F  = (size_t)BB * HU;           // 38,400
static constexpr size_t FLAG_I = (size_t)GR * GC;           // 240 monotonic step counters

typedef __attribute__((ext_vector_type(8))) short bf16x8;
typedef __attribute__((ext_vector_type(4))) float f32x4;

__device__ __forceinline__ short f2bf(float f) {
    unsigned u = __float_as_uint(f);
    u += 0x7fff + ((u >> 16) & 1);   // round-to-nearest-even
    return (short)(u >> 16);
}
__device__ __forceinline__ float sigm(float x) { return 1.f / (1.f + __expf(-x)); }
__device__ __forceinline__ float tanh_(float x) { return 1.f - 2.f / (__expf(2.f * x) + 1.f); }

// ---------------------------------------------------------------------------
// init: zero h_buf, c_state, flags, out[0]  (ws is poisoned 0xAA every launch)
// ---------------------------------------------------------------------------
__global__ void init_kernel(float* __restrict__ hbuf, int* __restrict__ flags,
                            float* __restrict__ out) {
    size_t i = (size_t)blockIdx.x * 256 + threadIdx.x;
    if (i < HBUF_F + CST_F) hbuf[i] = 0.f;       // h_buf + c_state contiguous
    if (i < FLAG_I) flags[i] = 0;
    if (i == 0) out[0] = 0.f;
}

// ---------------------------------------------------------------------------
// Phase 1: zx[b][tc][n] = emb[ids[b][t0+tc]] @ W_lstm[0:300] + b_lstm   (bf16 MFMA)
// WG tile: M=256 rows, N=80 cols, K=320 (300 zero-padded). 4 waves, wave = 64x80.
// grid = (8192/256, 1200/80) = (32, 15)
// ---------------------------------------------------------------------------
__global__ __launch_bounds__(256) void zx_gemm(
    const float* __restrict__ emb, const int* __restrict__ ids,
    const float* __restrict__ Wl, const float* __restrict__ bl,
    float* __restrict__ zx, int t0)
{
    __shared__ short A_l[256 * 40];   // [row][k] pad 32->40 shorts
    __shared__ short B_l[80 * 40];    // [col][k] (transposed)
    __shared__ int   ids_l[256];

    const int tid = threadIdx.x;
    const int m0  = blockIdx.x * 256;
    const int n0  = blockIdx.y * 80;
    const int wv  = tid >> 6, ln = tid & 63;

    {   // per-row embedding id
        int m = m0 + tid;
        int b = m >> 6, tc = m & (CHUNK - 1);
        ids_l[tid] = ids[b * TT + t0 + tc];
    }

    f32x4 acc[4][5];
    for (int i = 0; i < 4; ++i)
        for (int j = 0; j < 5; ++j)
            acc[i][j] = (f32x4){0.f, 0.f, 0.f, 0.f};

    for (int k0 = 0; k0 < 320; k0 += 32) {
        __syncthreads();
        // stage A: 256 rows x 32 k, one row per thread (float4 x8, guard k<300)
        {
            const float* src = emb + (size_t)ids_l[tid] * DD;
            #pragma unroll
            for (int q = 0; q < 8; ++q) {
                int kg = k0 + q * 4;
                float4 v;
                if (kg < DD) v = *(const float4*)(src + kg);
                else         v = make_float4(0.f, 0.f, 0.f, 0.f);
                short4 s; s.x = f2bf(v.x); s.y = f2bf(v.y); s.z = f2bf(v.z); s.w = f2bf(v.w);
                *(short4*)&A_l[tid * 40 + q * 4] = s;
            }
        }
        // stage B (transposed): 80 cols x 32 k. thread: kk=tid>>3, 10 cols each
        {
            int kk = tid >> 3;
            int c0 = (tid & 7) * 10;
            int kg = k0 + kk;
            #pragma unroll
            for (int c = 0; c < 10; ++c) {
                float v = (kg < DD) ? Wl[(size_t)kg * N4H + n0 + c0 + c] : 0.f;
                B_l[(c0 + c) * 40 + kk] = f2bf(v);
            }
        }
        __syncthreads();
        // fragments + MFMA. A[m=lane&15][k=quad*8+j], B[k=quad*8+j][n=lane&15]
        const int koff = (ln >> 4) * 8;
        bf16x8 afr[4], bfr[5];
        #pragma unroll
        for (int mt = 0; mt < 4; ++mt) {
            int row = wv * 64 + mt * 16 + (ln & 15);
            afr[mt] = *(const bf16x8*)&A_l[row * 40 + koff];
        }
        #pragma unroll
        for (int nt = 0; nt < 5; ++nt) {
            int col = nt * 16 + (ln & 15);
            bfr[nt] = *(const bf16x8*)&B_l[col * 40 + koff];
        }
        #pragma unroll
        for (int mt = 0; mt < 4; ++mt)
            #pragma unroll
            for (int nt = 0; nt < 5; ++nt)
                acc[mt][nt] = __builtin_amdgcn_mfma_f32_16x16x32_bf16(
                    afr[mt], bfr[nt], acc[mt][nt], 0, 0, 0);
    }
    // epilogue: C row=(lane>>4)*4+reg, col=lane&15; add bias
    #pragma unroll
    for (int mt = 0; mt < 4; ++mt) {
        #pragma unroll
        for (int nt = 0; nt < 5; ++nt) {
            #pragma unroll
            for (int rg = 0; rg < 4; ++rg) {
                int row = m0 + wv * 64 + mt * 16 + (ln >> 4) * 4 + rg;
                int col = n0 + nt * 16 + (ln & 15);
                zx[(size_t)row * N4H + col] = acc[mt][nt][rg] + bl[col];
            }
        }
    }
}

// ---------------------------------------------------------------------------
// Phase 2: persistent recurrent kernel. 240 WGs = 16 row-groups x 15 col-groups.
// W_h slice lives in registers (thread owns 4 cols x 25 k = 100 VGPRs).
// Sync: FENCE-FREE relaxed agent-scope atomics. h exchange + flags go straight
// to the coherence point (sc0/sc1 coherent load/store) — no buffer_inv /
// buffer_wbl2 on the critical path, L2 stays warm for zx.
// flags[rg*GC+cg] is a monotonic "steps completed" counter per producer WG.
// ---------------------------------------------------------------------------
__global__ __launch_bounds__(256, 1) void lstm_rec(
    const float* __restrict__ zx, const float* __restrict__ Wl,
    const int* __restrict__ lens, float* __restrict__ hbuf,
    float* __restrict__ cst, int* __restrict__ flags, int t0)
{
    const int tid = threadIdx.x;
    const int rg  = blockIdx.x % GR;
    const int cgi = blockIdx.x / GR;
    const int r0  = rg * RPW;
    const int u0  = cgi * UPW;

    // GEMM role: cc in 0..19 (4 cols), kc in 0..11 (25 k); tid>=240 idle in GEMM
    const int cc = tid % 20;
    int kc = tid / 20;
    const bool gemm_act = (kc < KCH);
    if (!gemm_act) kc = KCH - 1;      // clamp so weight loads stay in-bounds

    // local col -> global gate col (4 consecutive cols never span a gate: 20%4==0)
    const int lc0  = cc * 4;
    const int gate = lc0 / UPW;
    const int ncol = 300 * gate + u0 + (lc0 % UPW);

    // W_h slice: unconditional load -> encourage full register residency
    float4 w[KLEN];
    #pragma unroll
    for (int j = 0; j < KLEN; ++j) {
        int kh = kc * KLEN + j;  // h index
        w[j] = *(const float4*)(Wl + (size_t)(DD + kh) * N4H + ncol);
    }

    __shared__ float h_l[RPW][304];        // staged h_{t-1}, full 300 cols
    __shared__ float zp[KCH][RPW][80];     // k-chunk partial sums
    __shared__ float c_l[RPW][UPW];        // private cell state slice

    // gate role (tid < 160): u = tid%20, r = tid/20
    const int g_u = tid % UPW, g_r = tid / UPW;
    int mylen = 0;
    if (tid < RPW * UPW) {
        c_l[g_r][g_u] = cst[(size_t)(r0 + g_r) * HU + u0 + g_u];
        mylen = lens[r0 + g_r];
    }
    __syncthreads();

    for (int tc = 0; tc < CHUNK; ++tc) {
        const int t = t0 + tc;

        // prefetch zx for this step (independent of h; normal cached loads)
        float z_pre[4];
        if (tid < RPW * UPW) {
            const float* zrow = zx + ((size_t)(r0 + g_r) * CHUNK + tc) * N4H;
            #pragma unroll
            for (int gg = 0; gg < 4; ++gg)
                z_pre[gg] = zrow[300 * gg + u0 + g_u];
        }

        // wait: all GC producers of this row-group finished step t-1.
        // RELAXED polls — no buffer_inv storm. One flag per polling lane.
        if (t > 0) {
            if (tid < GC) {
                const int* fp = &flags[rg * GC + tid];
                while (__hip_atomic_load(fp, __ATOMIC_RELAXED,
                                         __HIP_MEMORY_SCOPE_AGENT) < t) {
                    __builtin_amdgcn_s_sleep(1);
                }
            }
            __syncthreads();
        }

        // stage h_{t-1} (parity t&1) via coherent 8B loads (bypass stale caches)
        {
            const unsigned long long* hsrc =
                (const unsigned long long*)(hbuf + (size_t)(t & 1) * BB * HU);
            for (int i = tid; i < RPW * 150; i += 256) {
                int r = i / 150, kk = i - r * 150;
                unsigned long long v = __hip_atomic_load(
                    hsrc + (size_t)(r0 + r) * 150 + kk,
                    __ATOMIC_RELAXED, __HIP_MEMORY_SCOPE_AGENT);
                *(unsigned long long*)&h_l[r][kk * 2] = v;
            }
        }
        __syncthreads();

        // h @ W_h partials: per thread 8 rows x 25 k x 4 cols (w in registers)
        {
            #pragma unroll
            for (int r = 0; r < RPW; ++r) {
                float ax = 0.f, ay = 0.f, az = 0.f, aw = 0.f;
                #pragma unroll
                for (int j = 0; j < KLEN; ++j) {
                    float hv = h_l[r][kc * KLEN + j];
                    ax += hv * w[j].x; ay += hv * w[j].y;
                    az += hv * w[j].z; aw += hv * w[j].w;
                }
                if (gemm_act) {
                    float4 o; o.x = ax; o.y = ay; o.z = az; o.w = aw;
                    *(float4*)&zp[kc][r][lc0] = o;
                }
            }
        }
        __syncthreads();

        // reduce + gates + h/c update (160 threads); h store is coherent
        if (tid < RPW * UPW) {
            const int b = r0 + g_r;
            float z4[4];
            #pragma unroll
            for (int gg = 0; gg < 4; ++gg) {
                float s = z_pre[gg];
                #pragma unroll
                for (int k2 = 0; k2 < KCH; ++k2) s += zp[k2][g_r][gg * UPW + g_u];
                z4[gg] = s;
            }
            float ig = sigm(z4[0]);
            float jg = tanh_(z4[1]);
            float fg = sigm(z4[2] + 1.0f);   // FORGET_BIAS
            float og = sigm(z4[3]);
            float c_old = c_l[g_r][g_u];
            float c_new = c_old * fg + ig * jg;
            float h_new = tanh_(c_new) * og;
            bool upd = (t < mylen);
            float h_old = h_l[g_r][u0 + g_u];
            float ho = upd ? h_new : h_old;
            float co = upd ? c_new : c_old;
            c_l[g_r][g_u] = co;
            __hip_atomic_store(
                &hbuf[(size_t)((t + 1) & 1) * BB * HU + (size_t)b * HU + u0 + g_u],
                ho, __ATOMIC_RELAXED, __HIP_MEMORY_SCOPE_AGENT);
        }
        // drain h stores (coherent, already at coherence point once ack'd),
        // then barrier, then publish step counter. No cache maintenance ops.
        asm volatile("s_waitcnt vmcnt(0)" ::: "memory");
        __syncthreads();
        if (tid == 0)
            __hip_atomic_store(&flags[rg * GC + cgi], t + 1,
                               __ATOMIC_RELAXED, __HIP_MEMORY_SCOPE_AGENT);
    }
    __syncthreads();
    if (tid < RPW * UPW)
        cst[(size_t)(r0 + g_r) * HU + u0 + g_u] = c_l[g_r][g_u];
}

// ---------------------------------------------------------------------------
// Phase 3: logits = h_final @ W_dense + b_dense; log-softmax NLL; mean loss.
// One wave per batch row. h_final is in h_buf parity 0 (T=512 even).
// ---------------------------------------------------------------------------
__global__ __launch_bounds__(64) void cls_kernel(
    const float* __restrict__ hbuf, const float* __restrict__ Wd,
    const float* __restrict__ bd, const int* __restrict__ labels,
    float* __restrict__ out)
{
    const int b = blockIdx.x;
    const int ln = threadIdx.x;
    const float* h = hbuf + (size_t)b * HU;   // parity 0
    float p0 = 0.f, p1 = 0.f, p2 = 0.f;
    for (int k = ln; k < HU; k += 64) {
        float hv = h[k];
        p0 += hv * Wd[k * 3 + 0];
        p1 += hv * Wd[k * 3 + 1];
        p2 += hv * Wd[k * 3 + 2];
    }
    #pragma unroll
    for (int off = 32; off > 0; off >>= 1) {
        p0 += __shfl_down(p0, off);
        p1 += __shfl_down(p1, off);
        p2 += __shfl_down(p2, off);
    }
    if (ln == 0) {
        float l0 = p0 + bd[0], l1 = p1 + bd[1], l2 = p2 + bd[2];
        float m = fmaxf(l0, fmaxf(l1, l2));
        float lse = m + logf(__expf(l0 - m) + __expf(l1 - m) + __expf(l2 - m));
        int lab = labels[b];
        float sel = (lab == 0) ? l0 : ((lab == 1) ? l1 : l2);
        float nll = lse - sel;
        out[1 + b * 3 + 0] = l0;
        out[1 + b * 3 + 1] = l1;
        out[1 + b * 3 + 2] = l2;
        atomicAdd(out, nll * (1.0f / BB));
    }
}

// ---------------------------------------------------------------------------
extern "C" void kernel_launch(void* const* d_in, const int* in_sizes, int n_in,
                              void* d_out, int out_size, void* d_ws, size_t ws_size,
                              hipStream_t stream) {
    const int*   ids  = (const int*)d_in[0];
    const int*   lens = (const int*)d_in[1];
    const int*   labs = (const int*)d_in[2];
    const float* emb  = (const float*)d_in[3];
    const float* Wl   = (const float*)d_in[4];
    const float* bl   = (const float*)d_in[5];
    const float* Wd   = (const float*)d_in[6];
    const float* bd   = (const float*)d_in[7];
    float* out = (float*)d_out;

    float* zx   = (float*)d_ws;
    float* hbuf = zx + ZX_F;
    float* cst  = hbuf + HBUF_F;
    int*   flags = (int*)(cst + CST_F);

    {   // zero h/c/flags/out[0]
        int n = (int)((HBUF_F + CST_F + 255) / 256);
        init_kernel<<<n, 256, 0, stream>>>(hbuf, flags, out);
    }
    for (int c = 0; c < NCHUNK; ++c) {
        int t0 = c * CHUNK;
        zx_gemm<<<dim3(32, 15), 256, 0, stream>>>(emb, ids, Wl, bl, zx, t0);
        lstm_rec<<<GR * GC, 256, 0, stream>>>(zx, Wl, lens, hbuf, cst, flags, t0);
    }
    cls_kernel<<<BB, 64, 0, stream>>>(hbuf, Wd, bd, labs, out);
}